// Round 1
// baseline (676.384 us; speedup 1.0000x reference)
//
#include <hip/hip_runtime.h>
#include <hip/hip_bf16.h>
#include <math.h>

// Problem constants
#define BATCH 4
#define CIN 64
#define HH 128
#define WW 128
#define HWP (HH*WW)   // 16384

// ws layout (floats):
//  OFF  : [4][B][18][HW]              = 4,718,592
//  CAT  : [B][256][HW]                = 16,777,216
//  DWT  : [4][9][64][64]              = 147,456   (dw transposed: [i][k][c][o])
//  OWT  : [4][64][9][18]              = 41,472    (ow transposed: [j][c][tap][o])
//  G    : [B][256]                    = 1,024
//  SCALE: [B][256]                    = 1,024
#define OFF_OFF   0
#define CAT_OFF   4718592
#define DWT_OFF   (CAT_OFF + 16777216)
#define OWT_OFF   (DWT_OFF + 147456)
#define G_OFF     (OWT_OFF + 41472)
#define SCALE_OFF (G_OFF + 1024)

__device__ __forceinline__ int rate_of(int i) {
    return (i == 0) ? 2 : (i == 1) ? 3 : (i == 2) ? 5 : 9;
}

// ---------------------------------------------------------------------------
// Kernel 1: transpose weights so inner-loop weight reads are contiguous
// wave-uniform (scalar-load friendly).
// DWT[((i*9+k)*64+c)*64+o] = dw[((i*64+o)*64+c)*9+k]
// OWT[((j*64+c)*9+tap)*18+o] = ow[((j*18+o)*64+c)*9+tap]
// ---------------------------------------------------------------------------
__global__ __launch_bounds__(256) void transpose_w_kernel(
    const float* __restrict__ dw, const float* __restrict__ ow,
    float* __restrict__ dwT, float* __restrict__ owT)
{
    int idx = blockIdx.x * 256 + threadIdx.x;
    if (idx < 147456) {
        int o = idx & 63;
        int c = (idx >> 6) & 63;
        int k = (idx >> 12) % 9;
        int i = idx / 36864;
        dwT[idx] = dw[((i * 64 + o) * 64 + c) * 9 + k];
    }
    int idx2 = idx - 147456;
    if (idx2 >= 0 && idx2 < 41472) {
        int o = idx2 % 18;
        int r = idx2 / 18;
        int tap = r % 9; r /= 9;
        int c = r & 63;
        int j = r >> 6;
        owT[idx2] = ow[((j * 18 + o) * 64 + c) * 9 + tap];
    }
}

// ---------------------------------------------------------------------------
// Kernel 2: offset conv.  For branch j: OFF[j][b][o][h][w] =
//   relu( sum_{c,tap} x[b,c,h+(iy-1)*d, w+(ix-1)*d] * ow[j][o][c][tap] + ob[j][o] )
// Block = 256 threads covering a 64(w) x 8(h) tile, 2 pixels per thread
// (rows ly and ly+4) so each uniform weight load feeds 2 FMAs.
// grid = (W/64=2, H/8=16, 4*B=16) with z = j*4+b
// ---------------------------------------------------------------------------
__global__ __launch_bounds__(256) void offset_conv_kernel(
    const float* __restrict__ x, const float* __restrict__ owT,
    const float* __restrict__ ob, float* __restrict__ off)
{
    const int t  = threadIdx.x;
    const int lx = t & 63, ly = t >> 6;           // ly in 0..3
    const int w0 = blockIdx.x * 64 + lx;
    const int h0 = blockIdx.y * 8 + ly;           // this thread: rows h0, h0+4
    const int z  = blockIdx.z;
    const int j  = z >> 2, b = z & 3;
    const int d  = rate_of(j);

    float acc0[18], acc1[18];
#pragma unroll
    for (int o = 0; o < 18; ++o) {
        float bv = ob[j * 18 + o];
        acc0[o] = bv; acc1[o] = bv;
    }

    const float* xb = x + b * CIN * HWP;
    for (int c = 0; c < CIN; ++c) {
        const float* xc = xb + c * HWP;
        const float* wp = owT + ((j * 64 + c) * 9) * 18;
#pragma unroll
        for (int tap = 0; tap < 9; ++tap) {
            const int iy = tap / 3, ix = tap % 3;
            const int xx = w0 + (ix - 1) * d;
            const int yA = h0 + (iy - 1) * d;
            const int yB = yA + 4;
            const bool vx = ((unsigned)xx < (unsigned)WW);
            float vA = (vx && (unsigned)yA < (unsigned)HH) ? xc[yA * WW + xx] : 0.f;
            float vB = (vx && (unsigned)yB < (unsigned)HH) ? xc[yB * WW + xx] : 0.f;
            const float* wt = wp + tap * 18;
#pragma unroll
            for (int o = 0; o < 18; ++o) {
                float wv = wt[o];
                acc0[o] = fmaf(vA, wv, acc0[o]);
                acc1[o] = fmaf(vB, wv, acc1[o]);
            }
        }
    }
    float* op = off + (size_t)z * 18 * HWP;
#pragma unroll
    for (int o = 0; o < 18; ++o) {
        op[o * HWP + h0 * WW + w0]       = fmaxf(acc0[o], 0.f);
        op[o * HWP + (h0 + 4) * WW + w0] = fmaxf(acc1[o], 0.f);
    }
}

// ---------------------------------------------------------------------------
// Kernel 3: deformable conv, branch i (dilation RATES[i], offsets from
// branch j=(i+3)%4).  1 pixel/thread, 64 output-channel accumulators.
// CAT[b][i*64+o][h][w] = sum_{k,c} bilin(x[b,c], py,px) * dw[i][o][c][k]
// grid = (W/64=2, H/4=32, 4*B=16) z = i*4+b, block 256 = 64(w) x 4(h)
// ---------------------------------------------------------------------------
__global__ __launch_bounds__(256) void deform_kernel(
    const float* __restrict__ x, const float* __restrict__ dwT,
    const float* __restrict__ off, float* __restrict__ cat)
{
    const int t  = threadIdx.x;
    const int lx = t & 63, ly = t >> 6;
    const int w  = blockIdx.x * 64 + lx;
    const int h  = blockIdx.y * 4 + ly;
    const int z  = blockIdx.z;
    const int i  = z >> 2, b = z & 3;
    const int d  = rate_of(i);
    const int j  = (i + 3) & 3;

    const int p = h * WW + w;
    const float* offp = off + ((size_t)(j * 4 + b) * 18) * HWP + p;
    const float* xb   = x + b * CIN * HWP;

    float acc[64];
#pragma unroll
    for (int o = 0; o < 64; ++o) acc[o] = 0.f;

#pragma unroll
    for (int k = 0; k < 9; ++k) {
        const int iy = k / 3, ix = k % 3;
        float dy = offp[(2 * k) * HWP];
        float dx = offp[(2 * k + 1) * HWP];
        float py = (float)(h + (iy - 1) * d) + dy;
        float px = (float)(w + (ix - 1) * d) + dx;
        float fy0 = floorf(py), fx0 = floorf(px);
        float wy1 = py - fy0, wx1 = px - fx0;
        float wy0 = 1.f - wy1, wx0 = 1.f - wx1;
        int y0 = (int)fy0, x0 = (int)fx0;
        int y1 = y0 + 1,  x1 = x0 + 1;
        bool vy0 = (unsigned)y0 < (unsigned)HH, vy1 = (unsigned)y1 < (unsigned)HH;
        bool vx0 = (unsigned)x0 < (unsigned)WW, vx1 = (unsigned)x1 < (unsigned)WW;
        int yc0 = min(max(y0, 0), HH - 1), yc1 = min(max(y1, 0), HH - 1);
        int xc0 = min(max(x0, 0), WW - 1), xc1 = min(max(x1, 0), WW - 1);
        // fold validity into the bilinear weights; always load clipped addr
        float w00 = (vy0 && vx0) ? wy0 * wx0 : 0.f;
        float w01 = (vy0 && vx1) ? wy0 * wx1 : 0.f;
        float w10 = (vy1 && vx0) ? wy1 * wx0 : 0.f;
        float w11 = (vy1 && vx1) ? wy1 * wx1 : 0.f;
        int a00 = yc0 * WW + xc0, a01 = yc0 * WW + xc1;
        int a10 = yc1 * WW + xc0, a11 = yc1 * WW + xc1;

        const float* wk = dwT + (size_t)(i * 9 + k) * 64 * 64;
        for (int c = 0; c < CIN; ++c) {
            const float* xc = xb + c * HWP;
            float v = xc[a00] * w00 + xc[a01] * w01 + xc[a10] * w10 + xc[a11] * w11;
            const float* wc = wk + c * 64;   // 64 consecutive, wave-uniform
#pragma unroll
            for (int o = 0; o < 64; ++o) acc[o] = fmaf(v, wc[o], acc[o]);
        }
    }
    float* cp = cat + ((size_t)(b * 256 + i * 64)) * HWP + p;
#pragma unroll
    for (int o = 0; o < 64; ++o) cp[(size_t)o * HWP] = acc[o];
}

// ---------------------------------------------------------------------------
// Kernel 4: per-(b,channel) spatial mean of CAT.  1024 blocks x 256 thr.
// ---------------------------------------------------------------------------
__global__ __launch_bounds__(256) void reduce_kernel(
    const float* __restrict__ cat, float* __restrict__ g)
{
    const int bc = blockIdx.x;                 // b*256 + ch
    const float* p = cat + (size_t)bc * HWP;
    float s = 0.f;
    for (int idx = threadIdx.x; idx < HWP; idx += 256) s += p[idx];
#pragma unroll
    for (int o = 32; o > 0; o >>= 1) s += __shfl_down(s, o, 64);
    __shared__ float ls[4];
    if ((threadIdx.x & 63) == 0) ls[threadIdx.x >> 6] = s;
    __syncthreads();
    if (threadIdx.x == 0) {
        g[bc] = (ls[0] + ls[1] + ls[2] + ls[3]) * (1.f / (float)HWP);
    }
}

// ---------------------------------------------------------------------------
// Kernel 5: SE MLP.  scale[b][ch] = 1 + sigmoid( relu(g@W1^T+b1) @ W2^T + b2 )
// single block, 256 threads.
// ---------------------------------------------------------------------------
__global__ __launch_bounds__(256) void se_kernel(
    const float* __restrict__ g,  const float* __restrict__ w1,
    const float* __restrict__ b1, const float* __restrict__ w2,
    const float* __restrict__ b2, float* __restrict__ scale)
{
    __shared__ float gs[1024];
    __shared__ float h1s[256];
    const int t = threadIdx.x;
#pragma unroll
    for (int q = 0; q < 4; ++q) gs[q * 256 + t] = g[q * 256 + t];
    __syncthreads();
    {
        int b = t >> 6, o = t & 63;
        float a = b1[o];
        for (int c = 0; c < 256; ++c)
            a = fmaf(gs[b * 256 + c], w1[o * 256 + c], a);
        h1s[t] = fmaxf(a, 0.f);
    }
    __syncthreads();
#pragma unroll
    for (int q = 0; q < 4; ++q) {
        int idx = q * 256 + t;
        int b = idx >> 8, cc = idx & 255;
        float a = b2[cc];
#pragma unroll 8
        for (int o = 0; o < 64; ++o)
            a = fmaf(h1s[b * 64 + o], w2[cc * 64 + o], a);
        scale[idx] = 1.f + 1.f / (1.f + expf(-a));
    }
}

// ---------------------------------------------------------------------------
// Kernel 6: gated sum epilogue.
// out[b,c,p] = x[b,c,p] + sum_i scale[b, i*64+c] * CAT[b, i*64+c, p]
// grid = 4*64*64 blocks of 256; block handles fixed (b,c), 256 pixels.
// ---------------------------------------------------------------------------
__global__ __launch_bounds__(256) void final_kernel(
    const float* __restrict__ x, const float* __restrict__ cat,
    const float* __restrict__ scale, float* __restrict__ out)
{
    const int gid = blockIdx.x;
    const int p = (gid & 63) * 256 + threadIdx.x;
    const int c = (gid >> 6) & 63;
    const int b = gid >> 12;
    const float s0 = scale[b * 256 + c];
    const float s1 = scale[b * 256 + 64 + c];
    const float s2 = scale[b * 256 + 128 + c];
    const float s3 = scale[b * 256 + 192 + c];
    const float* cb = cat + ((size_t)(b * 256 + c)) * HWP + p;
    float v = x[(size_t)(b * 64 + c) * HWP + p];
    v = fmaf(s0, cb[0 * 64 * HWP], v);
    v = fmaf(s1, cb[1 * 64 * HWP], v);
    v = fmaf(s2, cb[2 * 64 * HWP], v);
    v = fmaf(s3, cb[3 * 64 * HWP], v);
    out[(size_t)(b * 64 + c) * HWP + p] = v;
}

extern "C" void kernel_launch(void* const* d_in, const int* in_sizes, int n_in,
                              void* d_out, int out_size, void* d_ws, size_t ws_size,
                              hipStream_t stream) {
    const float* x  = (const float*)d_in[0];
    const float* dw = (const float*)d_in[1];
    const float* ow = (const float*)d_in[2];
    const float* ob = (const float*)d_in[3];
    const float* w1 = (const float*)d_in[4];
    const float* b1 = (const float*)d_in[5];
    const float* w2 = (const float*)d_in[6];
    const float* b2 = (const float*)d_in[7];
    float* out = (float*)d_out;
    float* ws  = (float*)d_ws;

    float* OFF   = ws + OFF_OFF;
    float* CAT   = ws + CAT_OFF;
    float* DWT   = ws + DWT_OFF;
    float* OWT   = ws + OWT_OFF;
    float* G     = ws + G_OFF;
    float* SCALE = ws + SCALE_OFF;

    transpose_w_kernel<<<738, 256, 0, stream>>>(dw, ow, DWT, OWT);
    offset_conv_kernel<<<dim3(2, 16, 16), 256, 0, stream>>>(x, OWT, ob, OFF);
    deform_kernel<<<dim3(2, 32, 16), 256, 0, stream>>>(x, DWT, OFF, CAT);
    reduce_kernel<<<1024, 256, 0, stream>>>(CAT, G);
    se_kernel<<<1, 256, 0, stream>>>(G, w1, b1, w2, b2, SCALE);
    final_kernel<<<16384, 256, 0, stream>>>(x, CAT, SCALE, out);
}